// Round 1
// baseline (177.015 us; speedup 1.0000x reference)
//
#include <hip/hip_runtime.h>
#include <stdint.h>

// ---- types ----
typedef __bf16 bf16x8 __attribute__((ext_vector_type(8)));
typedef float f32x4 __attribute__((ext_vector_type(4)));
typedef unsigned short us4 __attribute__((ext_vector_type(4)));

#define SEQ 2048
#define NHEADS 8

// async global->LDS, 16B per lane, LDS dest = wave-uniform base + lane*16
#define GLOAD_LDS16(gp, lp)                                                        \
  __builtin_amdgcn_global_load_lds(                                                \
      (const __attribute__((address_space(1))) void*)(uintptr_t)(const void*)(gp), \
      (__attribute__((address_space(3))) void*)(uintptr_t)(void*)(lp), 16, 0, 0)

__device__ __forceinline__ unsigned short f2bf(float f) {
  unsigned int u = __builtin_bit_cast(unsigned int, f);
  u += 0x7fffu + ((u >> 16) & 1u);  // RNE
  return (unsigned short)(u >> 16);
}

// ---------------- fp32 -> bf16 convert ----------------
__global__ void cvt_kernel(const float* __restrict__ src,
                           unsigned short* __restrict__ dst, int n4) {
  int i = blockIdx.x * blockDim.x + threadIdx.x;
  if (i >= n4) return;
  float4 v = ((const float4*)src)[i];
  us4 o;
  o.x = f2bf(v.x); o.y = f2bf(v.y); o.z = f2bf(v.z); o.w = f2bf(v.w);
  ((us4*)dst)[i] = o;
}

// ---------------- shared 128x128 B^T GEMM tile core ----------------
// C[128x128] = A[m0..+128][0..512) * B[n0..+128][0..512)^T, bf16 row-major ld=512.
// LDS tiles As/Bs: [128][64] bf16, XOR-swizzled in 8-elem col blocks: cb_s = cb ^ (row&7).
__device__ __forceinline__ void gemm_tile_bt(const unsigned short* __restrict__ A,
                                             const unsigned short* __restrict__ B,
                                             int m0, int n0,
                                             unsigned short* As, unsigned short* Bs,
                                             f32x4 (&acc)[4][4]) {
  const int tid = threadIdx.x;
  const int w = tid >> 6, lane = tid & 63;
  const int wr = w >> 1, wc = w & 1;
  const int lrow = lane & 15, q = lane >> 4;
  const int snb = w * 32 + (lane >> 3);  // staging row base (+ t*8)
  const int scb = lane & 7;              // staging col-block slot

#pragma unroll
  for (int i = 0; i < 4; ++i)
#pragma unroll
    for (int j = 0; j < 4; ++j)
#pragma unroll
      for (int r = 0; r < 4; ++r) acc[i][j][r] = 0.f;

  for (int kt = 0; kt < 8; ++kt) {  // K=512, BK=64
    __syncthreads();  // previous tile fully consumed
#pragma unroll
    for (int t = 0; t < 4; ++t) {
      int n = snb + t * 8;
      int cbg = scb ^ (n & 7);  // global col-block for this LDS slot
      GLOAD_LDS16(A + (size_t)(m0 + n) * 512 + kt * 64 + cbg * 8,
                  As + (w * 32 + t * 8) * 64);
      GLOAD_LDS16(B + (size_t)(n0 + n) * 512 + kt * 64 + cbg * 8,
                  Bs + (w * 32 + t * 8) * 64);
    }
    __syncthreads();  // staging landed (vmcnt drained by barrier)

    bf16x8 af[4][2], bfr[4][2];
#pragma unroll
    for (int i = 0; i < 4; ++i) {
      int m = wr * 64 + i * 16 + lrow;
#pragma unroll
      for (int kk = 0; kk < 2; ++kk) {
        int cb = (kk * 4 + q) ^ (m & 7);
        af[i][kk] = *(const bf16x8*)(As + m * 64 + cb * 8);
      }
    }
#pragma unroll
    for (int j = 0; j < 4; ++j) {
      int n = wc * 64 + j * 16 + lrow;
#pragma unroll
      for (int kk = 0; kk < 2; ++kk) {
        int cb = (kk * 4 + q) ^ (n & 7);
        bfr[j][kk] = *(const bf16x8*)(Bs + n * 64 + cb * 8);
      }
    }
#pragma unroll
    for (int i = 0; i < 4; ++i)
#pragma unroll
      for (int j = 0; j < 4; ++j) {
        acc[i][j] = __builtin_amdgcn_mfma_f32_16x16x32_bf16(af[i][0], bfr[j][0], acc[i][j], 0, 0, 0);
        acc[i][j] = __builtin_amdgcn_mfma_f32_16x16x32_bf16(af[i][1], bfr[j][1], acc[i][j], 0, 0, 0);
      }
  }
}

// ---------------- QKV projection ----------------
// z=0: Q -> [B,H,S,D]; z=1: K -> [B,H,S,D]; z=2: V -> Vt [B,H,D,S]
__global__ __launch_bounds__(256, 2) void qkv_kernel(
    const unsigned short* __restrict__ A, const unsigned short* __restrict__ Wq,
    const unsigned short* __restrict__ Wk, const unsigned short* __restrict__ Wv,
    unsigned short* __restrict__ Qo, unsigned short* __restrict__ Ko,
    unsigned short* __restrict__ Vto) {
  __shared__ unsigned short As[128 * 64];
  __shared__ unsigned short Bs[128 * 64];
  const int m0 = blockIdx.x * 128, n0 = blockIdx.y * 128, z = blockIdx.z;
  const unsigned short* Bp = (z == 0) ? Wq : (z == 1) ? Wk : Wv;
  f32x4 acc[4][4];
  gemm_tile_bt(A, Bp, m0, n0, As, Bs, acc);

  const int tid = threadIdx.x, w = tid >> 6, lane = tid & 63;
  const int wr = w >> 1, wc = w & 1, lcol = lane & 15, q = lane >> 4;
  if (z < 2) {
    unsigned short* outp = (z == 0) ? Qo : Ko;
#pragma unroll
    for (int i = 0; i < 4; ++i) {
      int gm0 = m0 + wr * 64 + i * 16 + q * 4;
#pragma unroll
      for (int j = 0; j < 4; ++j) {
        int gn = n0 + wc * 64 + j * 16 + lcol;
        int h = gn >> 6, d = gn & 63;
#pragma unroll
        for (int r = 0; r < 4; ++r) {
          int gm = gm0 + r;
          int b = gm >> 11, s = gm & 2047;
          outp[(((size_t)(b * NHEADS + h) * SEQ + s) << 6) + d] = f2bf(acc[i][j][r]);
        }
      }
    }
  } else {
#pragma unroll
    for (int i = 0; i < 4; ++i) {
      int gm0 = m0 + wr * 64 + i * 16 + q * 4;
      int b = gm0 >> 11, s0 = gm0 & 2047;  // 4 consecutive s, never crosses batch
#pragma unroll
      for (int j = 0; j < 4; ++j) {
        int gn = n0 + wc * 64 + j * 16 + lcol;
        int h = gn >> 6, d = gn & 63;
        us4 v;
        v.x = f2bf(acc[i][j][0]); v.y = f2bf(acc[i][j][1]);
        v.z = f2bf(acc[i][j][2]); v.w = f2bf(acc[i][j][3]);
        *(us4*)(Vto + ((size_t)(b * NHEADS + h) * 64 + d) * SEQ + s0) = v;
      }
    }
  }
}

// ---------------- sigmoid attention ----------------
// grid (16 q-tiles, 32 bh). O[b,s,h,d] += sigmoid(QK/8 - log S) @ V
__global__ __launch_bounds__(256, 2) void attn_kernel(
    const unsigned short* __restrict__ Qw, const unsigned short* __restrict__ Kw,
    const unsigned short* __restrict__ Vtw, unsigned short* __restrict__ Ow) {
  __shared__ unsigned short lds[32768];   // 64 KB
  unsigned short* Ks = lds;               // [128][64]
  unsigned short* Vts = lds + 8192;       // [64][128]
  unsigned short* Ps = lds + 16384;       // [128][128], aliases Qs
  unsigned short* Qs = Ps;                // [128][64]

  const int tid = threadIdx.x, w = tid >> 6, lane = tid & 63;
  const int wr = w >> 1, wc = w & 1, lrow = lane & 15, q = lane >> 4;
  const int bh = blockIdx.y, q0 = blockIdx.x * 128;
  const unsigned short* Qp = Qw + ((size_t)bh * SEQ + q0) * 64;
  const unsigned short* Kp = Kw + (size_t)bh * SEQ * 64;
  const unsigned short* Vp = Vtw + (size_t)bh * 64 * SEQ;

  const int snb = w * 32 + (lane >> 3), scb = lane & 7;   // [128][64] staging
  const int vnb = w * 16 + (lane >> 4), vcb = lane & 15;  // [64][128] staging

  // stage Q tile
#pragma unroll
  for (int t = 0; t < 4; ++t) {
    int n = snb + t * 8;
    int cbg = scb ^ (n & 7);
    GLOAD_LDS16(Qp + (size_t)n * 64 + cbg * 8, Qs + (w * 32 + t * 8) * 64);
  }
  __syncthreads();

  bf16x8 qa[4][2];
#pragma unroll
  for (int i = 0; i < 4; ++i) {
    int m = wr * 64 + i * 16 + lrow;
#pragma unroll
    for (int kk = 0; kk < 2; ++kk) {
      int cb = (kk * 4 + q) ^ (m & 7);
      qa[i][kk] = *(const bf16x8*)(Qs + m * 64 + cb * 8);
    }
  }

  f32x4 oacc[4][2];
#pragma unroll
  for (int i = 0; i < 4; ++i)
#pragma unroll
    for (int j = 0; j < 2; ++j)
#pragma unroll
      for (int r = 0; r < 4; ++r) oacc[i][j][r] = 0.f;

  const float c1 = -0.18033688011112042f;  // -(1/8)*log2(e); bias: +11 = log2(2048)

  for (int kt = 0; kt < 16; ++kt) {
    __syncthreads();  // (a) all reads of Ks/Vts/Ps (and qa at kt=0) done
#pragma unroll
    for (int t = 0; t < 4; ++t) {
      int n = snb + t * 8;
      int cbg = scb ^ (n & 7);
      GLOAD_LDS16(Kp + (size_t)(kt * 128 + n) * 64 + cbg * 8, Ks + (w * 32 + t * 8) * 64);
    }
#pragma unroll
    for (int t = 0; t < 4; ++t) {
      int n = vnb + t * 4;
      int cbg = vcb ^ (n & 15);
      GLOAD_LDS16(Vp + (size_t)n * SEQ + kt * 128 + cbg * 8, Vts + (w * 16 + t * 4) * 128);
    }
    __syncthreads();  // (b) staging landed

    // QK^T -> sacc (128x128 tile, K=64)
    f32x4 sacc[4][4];
#pragma unroll
    for (int i = 0; i < 4; ++i)
#pragma unroll
      for (int j = 0; j < 4; ++j)
#pragma unroll
        for (int r = 0; r < 4; ++r) sacc[i][j][r] = 0.f;
    bf16x8 kb[4][2];
#pragma unroll
    for (int j = 0; j < 4; ++j) {
      int n = wc * 64 + j * 16 + lrow;
#pragma unroll
      for (int kk = 0; kk < 2; ++kk) {
        int cb = (kk * 4 + q) ^ (n & 7);
        kb[j][kk] = *(const bf16x8*)(Ks + n * 64 + cb * 8);
      }
    }
#pragma unroll
    for (int i = 0; i < 4; ++i)
#pragma unroll
      for (int j = 0; j < 4; ++j) {
        sacc[i][j] = __builtin_amdgcn_mfma_f32_16x16x32_bf16(qa[i][0], kb[j][0], sacc[i][j], 0, 0, 0);
        sacc[i][j] = __builtin_amdgcn_mfma_f32_16x16x32_bf16(qa[i][1], kb[j][1], sacc[i][j], 0, 0, 0);
      }

    // sigmoid -> Ps (C-layout -> LDS, XOR swizzle cb^(row&15))
#pragma unroll
    for (int i = 0; i < 4; ++i) {
      int prow0 = wr * 64 + i * 16 + q * 4;
#pragma unroll
      for (int j = 0; j < 4; ++j) {
        int pcol = wc * 64 + j * 16 + lrow;
        int cb = pcol >> 3, ci = pcol & 7;
#pragma unroll
        for (int r = 0; r < 4; ++r) {
          int prow = prow0 + r;
          float e = __builtin_amdgcn_exp2f(__builtin_fmaf(sacc[i][j][r], c1, 11.0f));
          float p = __builtin_amdgcn_rcpf(1.0f + e);
          Ps[prow * 128 + ((cb ^ (prow & 15)) * 8) + ci] = f2bf(p);
        }
      }
    }
    __syncthreads();  // (c) Ps complete

    // O += P @ V  (M=128,N=64,K=128; wave: rows wr*64, cols wc*32)
#pragma unroll
    for (int ks = 0; ks < 4; ++ks) {
      bf16x8 pa[4], vb[2];
#pragma unroll
      for (int i2 = 0; i2 < 4; ++i2) {
        int m = wr * 64 + i2 * 16 + lrow;
        int cb = (ks * 4 + q) ^ (m & 15);
        pa[i2] = *(const bf16x8*)(Ps + m * 128 + cb * 8);
      }
#pragma unroll
      for (int j2 = 0; j2 < 2; ++j2) {
        int n = wc * 32 + j2 * 16 + lrow;
        int cb = (ks * 4 + q) ^ (n & 15);
        vb[j2] = *(const bf16x8*)(Vts + n * 128 + cb * 8);
      }
#pragma unroll
      for (int i2 = 0; i2 < 4; ++i2)
#pragma unroll
        for (int j2 = 0; j2 < 2; ++j2)
          oacc[i2][j2] = __builtin_amdgcn_mfma_f32_16x16x32_bf16(pa[i2], vb[j2], oacc[i2][j2], 0, 0, 0);
    }
  }

  // epilogue: O -> [B,S,H*D] bf16
  const int b = bh >> 3, h = bh & 7;
#pragma unroll
  for (int i2 = 0; i2 < 4; ++i2) {
#pragma unroll
    for (int j2 = 0; j2 < 2; ++j2) {
      int d = wc * 32 + j2 * 16 + lrow;
#pragma unroll
      for (int r = 0; r < 4; ++r) {
        int row = wr * 64 + i2 * 16 + q * 4 + r;
        int s = q0 + row;
        Ow[((size_t)(b * SEQ + s) * NHEADS + h) * 64 + d] = f2bf(oacc[i2][j2][r]);
      }
    }
  }
}

// ---------------- output projection (fp32 out) ----------------
__global__ __launch_bounds__(256, 2) void oproj_kernel(
    const unsigned short* __restrict__ A, const unsigned short* __restrict__ Wo,
    float* __restrict__ out) {
  __shared__ unsigned short As[128 * 64];
  __shared__ unsigned short Bs[128 * 64];
  const int m0 = blockIdx.x * 128, n0 = blockIdx.y * 128;
  f32x4 acc[4][4];
  gemm_tile_bt(A, Wo, m0, n0, As, Bs, acc);

  const int tid = threadIdx.x, w = tid >> 6, lane = tid & 63;
  const int wr = w >> 1, wc = w & 1, lcol = lane & 15, q = lane >> 4;
#pragma unroll
  for (int i = 0; i < 4; ++i) {
    int gm0 = m0 + wr * 64 + i * 16 + q * 4;
#pragma unroll
    for (int j = 0; j < 4; ++j) {
      int gn = n0 + wc * 64 + j * 16 + lcol;
#pragma unroll
      for (int r = 0; r < 4; ++r)
        out[(size_t)(gm0 + r) * 512 + gn] = acc[i][j][r];
    }
  }
}

// ---------------- launch ----------------
extern "C" void kernel_launch(void* const* d_in, const int* in_sizes, int n_in,
                              void* d_out, int out_size, void* d_ws, size_t ws_size,
                              hipStream_t stream) {
  const float* x = (const float*)d_in[0];
  const float* Wq = (const float*)d_in[1];
  const float* Wk = (const float*)d_in[2];
  const float* Wv = (const float*)d_in[3];
  const float* Wo = (const float*)d_in[4];
  float* out = (float*)d_out;
  char* ws = (char*)d_ws;

  unsigned short* xb  = (unsigned short*)(ws + 0);         // 8 MB  [8192][512]
  unsigned short* wqb = (unsigned short*)(ws + 8388608);   // 512 KB
  unsigned short* wkb = (unsigned short*)(ws + 8912896);
  unsigned short* wvb = (unsigned short*)(ws + 9437184);
  unsigned short* wob = (unsigned short*)(ws + 9961472);
  unsigned short* Qw  = (unsigned short*)(ws + 10485760);  // 8 MB  [B,H,S,D]
  unsigned short* Kw  = (unsigned short*)(ws + 18874368);  // 8 MB  [B,H,S,D]
  unsigned short* Vtw = (unsigned short*)(ws + 27262976);  // 8 MB  [B,H,D,S]
  unsigned short* Ow  = (unsigned short*)(ws + 35651584);  // 8 MB  [B,S,H*D]

  cvt_kernel<<<4096, 256, 0, stream>>>(x, xb, 4194304 / 4);
  cvt_kernel<<<256, 256, 0, stream>>>(Wq, wqb, 262144 / 4);
  cvt_kernel<<<256, 256, 0, stream>>>(Wk, wkb, 262144 / 4);
  cvt_kernel<<<256, 256, 0, stream>>>(Wv, wvb, 262144 / 4);
  cvt_kernel<<<256, 256, 0, stream>>>(Wo, wob, 262144 / 4);

  qkv_kernel<<<dim3(64, 4, 3), 256, 0, stream>>>(xb, wqb, wkb, wvb, Qw, Kw, Vtw);
  attn_kernel<<<dim3(16, 32), 256, 0, stream>>>(Qw, Kw, Vtw, Ow);
  oproj_kernel<<<dim3(64, 4), 256, 0, stream>>>(Ow, wob, out);
}